// Round 9
// baseline (194.111 us; speedup 1.0000x reference)
//
#include <hip/hip_runtime.h>
#include <stdint.h>

// Batched tiny MLP [B,13]->16->(30x 16->16 relu)->1, fp32 in/out, f16 MFMA.
// Transposed formulation: mfma_f32_16x16x16_f16 D layout == B layout, so each
// layer's relu'd output is the next layer's B fragment in-register.
// R21: force the MFMA||VALU interleave with sched_group_barrier. R20's
// source-level pipeline was a null (76us, MfmaUtil 36.5, VALU 52 -- IDENTICAL
// to R18): the scheduler ignored source order and re-clustered into bursts.
// Counter accounting is now serial-issue-complete: 36% MFMA (66k cyc/SIMD =
// the 16.2cyc x 4096 tile-layer pipe floor) + 52% VALU (95k = 11.6 instr/
// tile-layer; relu floor is 4) + 12% stall = 100%. Discriminating test:
// T19 sched_group_barrier forces [2xDS_READ][8x(1 MFMA : 4 VALU)] per layer
// body -- compile-time reorder, dependency-safe. Source also pairs each MFMA
// with the previous group's relu so group-matching is trivial, keeping R20's
// half-layer-offset dataflow (consumer >= 6 instrs from producer).
// If same-wave MFMA/VALU overlap exists: time -> MFMA floor (~28us + mem).
// If null: MFMA hard-blocks issue ~16cyc (theory B) -> serial floor 67us,
// next round cuts the excess VALU (accvgpr traffic), not the schedule.
// Keeps R18/R20's proven-clean parts: rolled layer loop, direct coalesced
// dwordx4 gather (0 bank conflicts), 18KB LDS, waves_per_eu(4,4), no spill
// (WRITE_SIZE 8.2MB canary).
// Edge case: lane(col=15,g=3) k0=12 gather would read 2 dwords past x's end
// on the last tile (x is exactly 2097152*52B). That lane loads shifted by -3
// dwords and selects v[3] as k=12, zeros for k>=13.

typedef __attribute__((ext_vector_type(4))) _Float16 half4v;
typedef __attribute__((ext_vector_type(2))) _Float16 h2;
typedef __attribute__((ext_vector_type(4))) float float4v;

#define S_IN 13
#define H 16
#define NL 32            // mfma layers: 0 = input, 1..30 = hidden, 31 = output
#define TPB 512
#define WPB 8            // waves per block
#define T 8              // 16-sample tiles per wave per iteration (2 groups of 4)
#define NBLOCKS 512      // fills 1024 SIMDs at 4 waves/SIMD
#define STRIDE (NBLOCKS * WPB * T)   // tiles per grid sweep = 32768

// LDS dword map (weights/bias only):
//   [0, 4096)     A-frags: 2 dwords (4 f16) per (L, lane)
//   [4096, 4608)  bias[L][m] fp32 (C-operand order)
#define LDS_DW 4608

__device__ __forceinline__ unsigned pkh(float a, float b) {
    return __builtin_bit_cast(unsigned, __builtin_amdgcn_cvt_pkrtz(a, b));
}

__device__ __forceinline__ half4v pack4h(float v0, float v1, float v2, float v3) {
    int2 p;
    p.x = (int)pkh(v0, v1);
    p.y = (int)pkh(v2, v3);
    return __builtin_bit_cast(half4v, p);
}

// cvt then packed-f16 relu: 2 cvt + 2 v_pk_max_f16
__device__ __forceinline__ half4v relu_pack4h(const float4v& d) {
    const h2 z = {(_Float16)0.f, (_Float16)0.f};
    h2 lo = __builtin_bit_cast(h2, pkh(d[0], d[1]));
    h2 hi = __builtin_bit_cast(h2, pkh(d[2], d[3]));
    lo = __builtin_elementwise_max(lo, z);
    hi = __builtin_elementwise_max(hi, z);
    int2 p;
    p.x = __builtin_bit_cast(int, lo);
    p.y = __builtin_bit_cast(int, hi);
    return __builtin_bit_cast(half4v, p);
}

// align-4 16B load (tile rows are dword- but not 16B-aligned: stride 13 dw)
__device__ __forceinline__ float4v ld4u(const float* p) {
    float4v r;
    __builtin_memcpy(&r, p, 16);
    return r;
}

__global__ __launch_bounds__(TPB)
__attribute__((amdgpu_waves_per_eu(4, 4)))
void mlp_kernel(const float* __restrict__ x,
                const float* __restrict__ W_in, const float* __restrict__ b_in,
                const float* __restrict__ W_h,  const float* __restrict__ b_h,
                const float* __restrict__ W_out,const float* __restrict__ b_out,
                float* __restrict__ out, int tiles)
{
    __shared__ unsigned lds[LDS_DW];
    const int tid = threadIdx.x;

    // ---- swizzle weights into f16 A-fragment layout in LDS (once/block) ----
    for (int s = tid; s < NL * 64; s += TPB) {
        const int L = s >> 6, ln = s & 63, m = ln & 15, gg = ln >> 4;
        float v[4];
#pragma unroll
        for (int i = 0; i < 4; ++i) {
            const int k = 4 * gg + i;
            if (L == 0)       v[i] = (k < S_IN) ? W_in[m * S_IN + k] : 0.f;
            else if (L <= 30) v[i] = W_h[(L - 1) * H * H + m * H + k];
            else              v[i] = (m == 0) ? W_out[k] : 0.f;
        }
        lds[s * 2]     = pkh(v[0], v[1]);
        lds[s * 2 + 1] = pkh(v[2], v[3]);
    }
    for (int s = tid; s < NL * H; s += TPB) {
        const int L = s >> 4, m = s & 15;
        float bv;
        if (L == 0)       bv = b_in[m];
        else if (L <= 30) bv = b_h[(L - 1) * H + m];
        else              bv = (m == 0) ? b_out[0] : 0.f;
        lds[4096 + s] = __float_as_uint(bv);
    }
    __syncthreads();

    const half4v* lA = (const half4v*)lds;             // [NL*64], 8B elems
    const float4v* lB = (const float4v*)(lds + 4096);  // [NL*4]

    const int lane = tid & 63;
    const int wv   = tid >> 6;
    const int g    = lane >> 4;
    const int col  = lane & 15;
    const bool edge = (col == 15) && (g == 3);         // lane 63: k0=12 overshoot
    const int goff = col * 13 + 4 * g - (edge ? 3 : 0);

    const int wave_id = blockIdx.x * WPB + wv;
    int tb = wave_id * T;
    if (tb >= tiles) return;

    float* op = out + (size_t)tb * 16 + lane;

    for (; tb < tiles; tb += STRIDE) {
        // ---- gather + pack, two batches of 4 tiles (short live ranges) ----
        const float* xp = x + (size_t)tb * 208 + goff;
        half4v bf[T];
#pragma unroll
        for (int half = 0; half < 2; ++half) {
            float4v v0 = ld4u(xp + (half * 4 + 0) * 208);
            float4v v1 = ld4u(xp + (half * 4 + 1) * 208);
            float4v v2 = ld4u(xp + (half * 4 + 2) * 208);
            float4v v3 = ld4u(xp + (half * 4 + 3) * 208);
            bf[half * 4 + 0] = pack4h(edge ? v0[3] : v0[0], edge ? 0.f : v0[1],
                                      edge ? 0.f : v0[2],  edge ? 0.f : v0[3]);
            bf[half * 4 + 1] = pack4h(edge ? v1[3] : v1[0], edge ? 0.f : v1[1],
                                      edge ? 0.f : v1[2],  edge ? 0.f : v1[3]);
            bf[half * 4 + 2] = pack4h(edge ? v2[3] : v2[0], edge ? 0.f : v2[1],
                                      edge ? 0.f : v2[2],  edge ? 0.f : v2[3]);
            bf[half * 4 + 3] = pack4h(edge ? v3[3] : v3[0], edge ? 0.f : v3[1],
                                      edge ? 0.f : v3[2],  edge ? 0.f : v3[3]);
        }

        // ---- layer 0 prologue: fill the pipeline ----
        half4v aC = lA[lane];
        float4v cC = lB[g];
        half4v aN = lA[64 + lane];
        float4v cN = lB[4 + g];
        float4v d0[4], d1[4];
#pragma unroll
        for (int t = 0; t < 4; ++t)
            d0[t] = __builtin_amdgcn_mfma_f32_16x16x16f16(aC, bf[t], cC, 0, 0, 0);
#pragma unroll
        for (int t = 0; t < 4; ++t)
            d1[t] = __builtin_amdgcn_mfma_f32_16x16x16f16(aC, bf[4 + t], cC, 0, 0, 0);
#pragma unroll
        for (int t = 0; t < 4; ++t)
            bf[t] = relu_pack4h(d0[t]);
        aC = aN; cC = cN;

        // ---- layers 1..30: paired MFMA/relu + forced 1:4 interleave ----
        // invariant at top: bf[0..3]=relu'd L-1 g0; d1=raw L-1 g1 outputs
#pragma unroll 1
        for (int L = 1; L < NL - 1; ++L) {
            aN = lA[(L + 1) * 64 + lane];
            cN = lB[(L + 1) * 4 + g];
            // pair: MFMA g0(L) with relu g1(L-1)
#pragma unroll
            for (int t = 0; t < 4; ++t) {
                d0[t] = __builtin_amdgcn_mfma_f32_16x16x16f16(aC, bf[t], cC, 0, 0, 0);
                bf[4 + t] = relu_pack4h(d1[t]);
            }
            // pair: MFMA g1(L) with relu g0(L)
#pragma unroll
            for (int t = 0; t < 4; ++t) {
                d1[t] = __builtin_amdgcn_mfma_f32_16x16x16f16(aC, bf[4 + t], cC, 0, 0, 0);
                bf[t] = relu_pack4h(d0[t]);
            }
            // scheduling directive for this region:
            //   2x DS_READ first (next layer's A/bias), then 8x [1 MFMA, 4 VALU]
            __builtin_amdgcn_sched_group_barrier(0x100, 2, 0);   // DS_READ
#pragma unroll
            for (int i = 0; i < 8; ++i) {
                __builtin_amdgcn_sched_group_barrier(0x008, 1, 0);  // 1 MFMA
                __builtin_amdgcn_sched_group_barrier(0x002, 4, 0);  // 4 VALU
            }
            aC = aN; cC = cN;
        }

        // ---- output layer 31: W_out row 0 only; y[n] = D[0][n] ----
#pragma unroll
        for (int t = 0; t < 4; ++t) {
            float4v d = __builtin_amdgcn_mfma_f32_16x16x16f16(aC, bf[t], cC, 0, 0, 0);
            if (lane < 16) op[t * 16] = d[0];
        }
#pragma unroll
        for (int t = 0; t < 4; ++t)
            bf[4 + t] = relu_pack4h(d1[t]);
#pragma unroll
        for (int t = 0; t < 4; ++t) {
            float4v d = __builtin_amdgcn_mfma_f32_16x16x16f16(aC, bf[4 + t], cC, 0, 0, 0);
            if (lane < 16) op[(4 + t) * 16] = d[0];
        }
        op += (size_t)STRIDE * 16;
    }
}

extern "C" void kernel_launch(void* const* d_in, const int* in_sizes, int n_in,
                              void* d_out, int out_size, void* d_ws, size_t ws_size,
                              hipStream_t stream) {
    const float* x     = (const float*)d_in[0];
    const float* W_in  = (const float*)d_in[1];
    const float* b_in  = (const float*)d_in[2];
    const float* W_h   = (const float*)d_in[3];
    const float* b_h   = (const float*)d_in[4];
    const float* W_out = (const float*)d_in[5];
    const float* b_out = (const float*)d_in[6];
    float* out = (float*)d_out;

    const int tiles = out_size / 16;                       // 131072
    int blocks = (tiles + WPB * T - 1) / (WPB * T);
    if (blocks > NBLOCKS) blocks = NBLOCKS;
    mlp_kernel<<<blocks, TPB, 0, stream>>>(x, W_in, b_in, W_h, b_h, W_out, b_out,
                                           out, tiles);
}

// Round 11
// 189.356 us; speedup vs baseline: 1.0251x; 1.0251x over previous
//
#include <hip/hip_runtime.h>
#include <stdint.h>

// Batched tiny MLP [B,13]->16->(30x 16->16 relu)->1, fp32 in/out, f16 MFMA.
// Transposed formulation: mfma_f32_16x16x16_f16 D layout == B layout, so each
// layer's relu'd output is the next layer's B fragment in-register.
// R23: R22 with the inline-asm aliasing bug fixed. R22 (absmax 0.239) used
// "=v" WITHOUT early-clobber: inline-asm semantics let the allocator alias
// D with dead inputs (bf[t] dies right after its MFMA) and MFMA forbids
// D/source overlap (reads A/B across passes while writing D) => silent
// corruption. Fix: "=&v" early-clobber (D disjoint from A/B/C, no copies).
// Prologue + output layer revert to the BUILTIN mfma (compiler-managed
// hazards where a store/relu follows closely; ~16 builtin MFMAs per sweep
// is <1% cost). Steady 30-layer loop keeps asm: consumers >=12 instrs from
// producers, VALU->MFMA operand gaps >=3 instrs.
// Why this matters (R18-R21 evidence): VALU=11.6 instr/tile-layer = 4 relu
// + 0.75 copies + 8 accvgpr bounces (builtin MFMA puts C/D in AGPR half);
// busy-sum == runtime => issue-serial => removing 8 accvgpr ops predicts
// VALU 95k->40k cyc/SIMD, total ~121k cyc ~= 51us dispatch.
// Null outcome => compiler was already VGPR-form, serial floor is real,
// declare roofline. Keeps R18's proven-clean parts: rolled layer loop,
// direct coalesced dwordx4 gather (0 bank conflicts), 18KB LDS,
// waves_per_eu(4,4), no spill (WRITE_SIZE 8.2MB canary).
// Edge case: lane(col=15,g=3) k0=12 gather would read 2 dwords past x's end
// on the last tile (x is exactly 2097152*52B). That lane loads shifted by -3
// dwords and selects v[3] as k=12, zeros for k>=13.

typedef __attribute__((ext_vector_type(4))) _Float16 half4v;
typedef __attribute__((ext_vector_type(2))) _Float16 h2;
typedef __attribute__((ext_vector_type(4))) float float4v;

#define S_IN 13
#define H 16
#define NL 32            // mfma layers: 0 = input, 1..30 = hidden, 31 = output
#define TPB 512
#define WPB 8            // waves per block
#define T 8              // 16-sample tiles per wave per iteration (2 groups of 4)
#define NBLOCKS 512      // fills 1024 SIMDs at 4 waves/SIMD
#define STRIDE (NBLOCKS * WPB * T)   // tiles per grid sweep = 32768

// LDS dword map (weights/bias only):
//   [0, 4096)     A-frags: 2 dwords (4 f16) per (L, lane)
//   [4096, 4608)  bias[L][m] fp32 (C-operand order)
#define LDS_DW 4608

__device__ __forceinline__ unsigned pkh(float a, float b) {
    return __builtin_bit_cast(unsigned, __builtin_amdgcn_cvt_pkrtz(a, b));
}

__device__ __forceinline__ half4v pack4h(float v0, float v1, float v2, float v3) {
    int2 p;
    p.x = (int)pkh(v0, v1);
    p.y = (int)pkh(v2, v3);
    return __builtin_bit_cast(half4v, p);
}

// cvt then packed-f16 relu: 2 cvt + 2 v_pk_max_f16
__device__ __forceinline__ half4v relu_pack4h(const float4v& d) {
    const h2 z = {(_Float16)0.f, (_Float16)0.f};
    h2 lo = __builtin_bit_cast(h2, pkh(d[0], d[1]));
    h2 hi = __builtin_bit_cast(h2, pkh(d[2], d[3]));
    lo = __builtin_elementwise_max(lo, z);
    hi = __builtin_elementwise_max(hi, z);
    int2 p;
    p.x = __builtin_bit_cast(int, lo);
    p.y = __builtin_bit_cast(int, hi);
    return __builtin_bit_cast(half4v, p);
}

// MFMA pinned to architectural VGPRs. "=&v" early-clobber: D is guaranteed
// disjoint from A/B/C (MFMA forbids D/source overlap), and "v" class keeps
// all operands out of the AGPR half -- no v_accvgpr_read/write possible.
__device__ __forceinline__ float4v mfma16_v(half4v a, half4v b, float4v c) {
    float4v d;
    asm("v_mfma_f32_16x16x16_f16 %0, %1, %2, %3"
        : "=&v"(d) : "v"(a), "v"(b), "v"(c));
    return d;
}

// align-4 16B load (tile rows are dword- but not 16B-aligned: stride 13 dw)
__device__ __forceinline__ float4v ld4u(const float* p) {
    float4v r;
    __builtin_memcpy(&r, p, 16);
    return r;
}

__global__ __launch_bounds__(TPB)
__attribute__((amdgpu_waves_per_eu(4, 4)))
void mlp_kernel(const float* __restrict__ x,
                const float* __restrict__ W_in, const float* __restrict__ b_in,
                const float* __restrict__ W_h,  const float* __restrict__ b_h,
                const float* __restrict__ W_out,const float* __restrict__ b_out,
                float* __restrict__ out, int tiles)
{
    __shared__ unsigned lds[LDS_DW];
    const int tid = threadIdx.x;

    // ---- swizzle weights into f16 A-fragment layout in LDS (once/block) ----
    for (int s = tid; s < NL * 64; s += TPB) {
        const int L = s >> 6, ln = s & 63, m = ln & 15, gg = ln >> 4;
        float v[4];
#pragma unroll
        for (int i = 0; i < 4; ++i) {
            const int k = 4 * gg + i;
            if (L == 0)       v[i] = (k < S_IN) ? W_in[m * S_IN + k] : 0.f;
            else if (L <= 30) v[i] = W_h[(L - 1) * H * H + m * H + k];
            else              v[i] = (m == 0) ? W_out[k] : 0.f;
        }
        lds[s * 2]     = pkh(v[0], v[1]);
        lds[s * 2 + 1] = pkh(v[2], v[3]);
    }
    for (int s = tid; s < NL * H; s += TPB) {
        const int L = s >> 4, m = s & 15;
        float bv;
        if (L == 0)       bv = b_in[m];
        else if (L <= 30) bv = b_h[(L - 1) * H + m];
        else              bv = (m == 0) ? b_out[0] : 0.f;
        lds[4096 + s] = __float_as_uint(bv);
    }
    __syncthreads();

    const half4v* lA = (const half4v*)lds;             // [NL*64], 8B elems
    const float4v* lB = (const float4v*)(lds + 4096);  // [NL*4]

    const int lane = tid & 63;
    const int wv   = tid >> 6;
    const int g    = lane >> 4;
    const int col  = lane & 15;
    const bool edge = (col == 15) && (g == 3);         // lane 63: k0=12 overshoot
    const int goff = col * 13 + 4 * g - (edge ? 3 : 0);

    const int wave_id = blockIdx.x * WPB + wv;
    int tb = wave_id * T;
    if (tb >= tiles) return;

    float* op = out + (size_t)tb * 16 + lane;

    for (; tb < tiles; tb += STRIDE) {
        // ---- gather + pack, two batches of 4 tiles (short live ranges) ----
        const float* xp = x + (size_t)tb * 208 + goff;
        half4v bf[T];
#pragma unroll
        for (int half = 0; half < 2; ++half) {
            float4v v0 = ld4u(xp + (half * 4 + 0) * 208);
            float4v v1 = ld4u(xp + (half * 4 + 1) * 208);
            float4v v2 = ld4u(xp + (half * 4 + 2) * 208);
            float4v v3 = ld4u(xp + (half * 4 + 3) * 208);
            bf[half * 4 + 0] = pack4h(edge ? v0[3] : v0[0], edge ? 0.f : v0[1],
                                      edge ? 0.f : v0[2],  edge ? 0.f : v0[3]);
            bf[half * 4 + 1] = pack4h(edge ? v1[3] : v1[0], edge ? 0.f : v1[1],
                                      edge ? 0.f : v1[2],  edge ? 0.f : v1[3]);
            bf[half * 4 + 2] = pack4h(edge ? v2[3] : v2[0], edge ? 0.f : v2[1],
                                      edge ? 0.f : v2[2],  edge ? 0.f : v2[3]);
            bf[half * 4 + 3] = pack4h(edge ? v3[3] : v3[0], edge ? 0.f : v3[1],
                                      edge ? 0.f : v3[2],  edge ? 0.f : v3[3]);
        }

        // ---- layer 0 prologue (BUILTIN mfma: compiler-managed hazards) ----
        half4v aC = lA[lane];
        float4v cC = lB[g];
        half4v aN = lA[64 + lane];
        float4v cN = lB[4 + g];
        float4v d0[4], d1[4];
#pragma unroll
        for (int t = 0; t < 4; ++t)
            d0[t] = __builtin_amdgcn_mfma_f32_16x16x16f16(aC, bf[t], cC, 0, 0, 0);
#pragma unroll
        for (int t = 0; t < 4; ++t)
            d1[t] = __builtin_amdgcn_mfma_f32_16x16x16f16(aC, bf[4 + t], cC, 0, 0, 0);
#pragma unroll
        for (int t = 0; t < 4; ++t)
            bf[t] = relu_pack4h(d0[t]);
        aC = aN; cC = cN;

        // ---- layers 1..30: asm MFMA (arch-VGPR pinned), group-of-4 phases;
        //      every consumer >=12 instrs from its producer ----
        // invariant at top: bf[0..3]=relu'd L-1 g0; d1=raw L-1 g1 outputs
#pragma unroll 1
        for (int L = 1; L < NL - 1; ++L) {
            aN = lA[(L + 1) * 64 + lane];
            cN = lB[(L + 1) * 4 + g];
            // phase 1: MFMA g0(L)
#pragma unroll
            for (int t = 0; t < 4; ++t)
                d0[t] = mfma16_v(aC, bf[t], cC);
            // phase 2: relu g1(L-1)
#pragma unroll
            for (int t = 0; t < 4; ++t)
                bf[4 + t] = relu_pack4h(d1[t]);
            // phase 3: MFMA g1(L)
#pragma unroll
            for (int t = 0; t < 4; ++t)
                d1[t] = mfma16_v(aC, bf[4 + t], cC);
            // phase 4: relu g0(L)
#pragma unroll
            for (int t = 0; t < 4; ++t)
                bf[t] = relu_pack4h(d0[t]);
            aC = aN; cC = cN;
        }

        // ---- output layer 31 (BUILTIN mfma: store follows closely) ----
#pragma unroll
        for (int t = 0; t < 4; ++t) {
            float4v d = __builtin_amdgcn_mfma_f32_16x16x16f16(aC, bf[t], cC, 0, 0, 0);
            if (lane < 16) op[t * 16] = d[0];
        }
#pragma unroll
        for (int t = 0; t < 4; ++t)
            bf[4 + t] = relu_pack4h(d1[t]);
#pragma unroll
        for (int t = 0; t < 4; ++t) {
            float4v d = __builtin_amdgcn_mfma_f32_16x16x16f16(aC, bf[4 + t], cC, 0, 0, 0);
            if (lane < 16) op[(4 + t) * 16] = d[0];
        }
        op += (size_t)STRIDE * 16;
    }
}

extern "C" void kernel_launch(void* const* d_in, const int* in_sizes, int n_in,
                              void* d_out, int out_size, void* d_ws, size_t ws_size,
                              hipStream_t stream) {
    const float* x     = (const float*)d_in[0];
    const float* W_in  = (const float*)d_in[1];
    const float* b_in  = (const float*)d_in[2];
    const float* W_h   = (const float*)d_in[3];
    const float* b_h   = (const float*)d_in[4];
    const float* W_out = (const float*)d_in[5];
    const float* b_out = (const float*)d_in[6];
    float* out = (float*)d_out;

    const int tiles = out_size / 16;                       // 131072
    int blocks = (tiles + WPB * T - 1) / (WPB * T);
    if (blocks > NBLOCKS) blocks = NBLOCKS;
    mlp_kernel<<<blocks, TPB, 0, stream>>>(x, W_in, b_in, W_h, b_h, W_out, b_out,
                                           out, tiles);
}